// Round 4
// baseline (731.670 us; speedup 1.0000x reference)
//
#include <hip/hip_runtime.h>
#include <hip/hip_bf16.h>
#include <math.h>

// Problem constants
#define NNODES 200000
#define NGRAPH 100
#define HD     128      // H == NF == 128
#define NCH    3        // virtual channels
#define BN     64       // nodes per block
#define EROWS  (BN*NCH) // 192 e-rows per block
#define ESTR   132      // 128 data + 4 pad elems; pads: cols 128..130 = bf16 diff[3]
                        // row stride 264B -> 8B aligned; 66 dwords -> ~4-way banks (cheap)

typedef short short8  __attribute__((ext_vector_type(8)));
typedef short short4v __attribute__((ext_vector_type(4)));
typedef float f32x4   __attribute__((ext_vector_type(4)));

#define MFMA_16x16x32(a,b,c) __builtin_amdgcn_mfma_f32_16x16x32_bf16((a),(b),(c),0,0,0)

__device__ __forceinline__ float bf2f(unsigned short u) {
    return __uint_as_float(((unsigned int)u) << 16);
}
__device__ __forceinline__ unsigned short f2bf(float f) {
    unsigned int u = __float_as_uint(f);
    return (unsigned short)((u + 0x7fffu + ((u >> 16) & 1u)) >> 16);
}
__device__ __forceinline__ float silu_f(float x) {
    return x * __builtin_amdgcn_rcpf(1.0f + __expf(-x));  // rcp: 1 instr vs full div
}
// 8B-aligned LDS load of an 8-elem bf16 A-fragment (ESTR=132 rows are 8B aligned)
__device__ __forceinline__ short8 ld_frag8(const unsigned short* p) {
    short4v a = *(const short4v*)p;
    short4v b = *(const short4v*)(p + 4);
    short8 r;
    r[0] = a[0]; r[1] = a[1]; r[2] = a[2]; r[3] = a[3];
    r[4] = b[0]; r[5] = b[1]; r[6] = b[2]; r[7] = b[3];
    return r;
}

// ---------------------------------------------------------------------------
// Repack We1[0:128], We2, Wc1 (fp32) into bf16 MFMA B-fragment order:
//   rep[((ct*4+ks)*64 + lane)*8 + j] = bf16(W[ks*32 + (lane>>4)*8 + j][ct*16 + (lane&15)])
// ---------------------------------------------------------------------------
__global__ void repack_kernel(const float* __restrict__ We1,
                              const float* __restrict__ We2,
                              const float* __restrict__ Wc1,
                              const float* __restrict__ be1,
                              const float* __restrict__ be2,
                              const float* __restrict__ bc1,
                              const float* __restrict__ Wc2,
                              unsigned short* __restrict__ w1r,
                              unsigned short* __restrict__ w2r,
                              unsigned short* __restrict__ wc1r,
                              float* __restrict__ wlast,
                              float* __restrict__ be1f,
                              float* __restrict__ be2f,
                              float* __restrict__ bc1f,
                              float* __restrict__ wc2f) {
    int t = blockIdx.x * blockDim.x + threadIdx.x;
    if (t < 3 * 16384) {
        int m  = t / 16384;
        int e  = t % 16384;
        int j  = e & 7;
        int l  = (e >> 3) & 63;
        int ks = (e >> 9) & 3;
        int ct = e >> 11;
        int row = ks * 32 + (l >> 4) * 8 + j;
        int col = ct * 16 + (l & 15);
        const float*    src = (m == 0) ? We1 : ((m == 1) ? We2 : Wc1);
        unsigned short* dst = (m == 0) ? w1r : ((m == 1) ? w2r : wc1r);
        dst[e] = f2bf(src[row * 128 + col]);
    }
    if (t < 128) {
        wlast[t] = We1[256 * 128 + t];
        be1f[t]  = be1[t];
        be2f[t]  = be2[t];
        bc1f[t]  = bc1[t];
        wc2f[t]  = Wc2[t];
    }
}

// ---------------------------------------------------------------------------
// Q[b,c,h] = sum_k vnf[b,k,c] * We1[128+k, h]; one block per (b,c).
// ---------------------------------------------------------------------------
__global__ void q_kernel(const float* __restrict__ vnf,
                         const float* __restrict__ We1,
                         float* __restrict__ Q) {
    int b = blockIdx.x / NCH;
    int c = blockIdx.x % NCH;
    int t = threadIdx.x;   // 0..127
    __shared__ float v[128];
    v[t] = vnf[(b * 128 + t) * 3 + c];
    __syncthreads();
    float s = 0.0f;
    for (int k = 0; k < 128; ++k)
        s += v[k] * We1[(128 + k) * 128 + t];
    Q[(b * 3 + c) * 128 + t] = s;
}

// ---------------------------------------------------------------------------
// Main fused kernel: 64 nodes/block, 256 threads (4 waves), 3125 blocks.
// LDS total = 54150 B -> rounds to ~54.3 KB -> 3 blocks/CU.
// Register plan: GEMM2/3 are i-split (one 8xf32x4 accumulator live at a time,
// 32 regs) so peak live regs ~110 << 512/3 budget -> NO SPILLS (r3 lesson).
// Barriers: phase0->compute and compute->reduce only (rows wave-private,
// per-wave LDS ops are in-order).
// ---------------------------------------------------------------------------
__global__ __launch_bounds__(256, 3) void egcl_main(
    const float* __restrict__ node_feat,   // [N,128]
    const float* __restrict__ coord,       // [N,3]
    const float* __restrict__ vcoord,      // [B,3,C]
    const int*   __restrict__ batch,       // [N] sorted
    const unsigned short* __restrict__ w1r,
    const unsigned short* __restrict__ w2r,
    const unsigned short* __restrict__ wc1r,
    const float* __restrict__ Q,           // [B,C,H]
    const float* __restrict__ wlast,
    const float* __restrict__ be1f,
    const float* __restrict__ be2f,
    const float* __restrict__ bc1f,
    const float* __restrict__ wc2f,
    float* __restrict__ aggsum,            // [B,C,H]
    float* __restrict__ transsum,          // [B,3,C]
    float* __restrict__ cnt)               // [B]
{
    __shared__ __align__(16) unsigned short e_buf[EROWS * ESTR]; // 50688 B
    __shared__ float sradial[BN][3];        // 768 B (fp32: accuracy)
    __shared__ float s_s[EROWS];            // 768 B
    __shared__ float sagg[NCH * HD];        // 1536 B (fast-path M sums)
    __shared__ unsigned short sbatch[BN];   // 128 B
    __shared__ unsigned short sseg_start[BN + 1];
    __shared__ unsigned short sseg_b[BN];
    __shared__ int snseg;

    const int tid   = threadIdx.x;
    const int wave  = tid >> 6;
    const int lane  = tid & 63;
    const int lrow  = lane & 15;           // MFMA row (A) / col (D) index
    const int lkb   = (lane >> 4) * 8;     // k-offset base within 32-wide K step
    const int rq    = (lane >> 4) * 4;     // D row-group base
    const int node0 = blockIdx.x * BN;

    // ---- Phase 0 ----
    for (int k = tid; k < NCH * HD; k += 256) sagg[k] = 0.0f;   // fast-path acc
    if (tid < BN) {  // wave 0 only
        int n = node0 + tid;
        int b = batch[n];
        sbatch[tid] = (unsigned short)b;
        int prev = (tid > 0) ? batch[n - 1] : -1;
        unsigned long long mask = __ballot(b != prev);
        int ns = __popcll(mask);
        if (b != prev) {
            int idx = __popcll(mask & ((1ull << tid) - 1ull));
            sseg_start[idx] = (unsigned short)tid;
            sseg_b[idx]     = (unsigned short)b;
        }
        if (tid == 0) { sseg_start[ns] = BN; snseg = ns; }
        float cx = coord[n * 3 + 0];
        float cy = coord[n * 3 + 1];
        float cz = coord[n * 3 + 2];
        for (int c = 0; c < 3; ++c) {
            float dx = vcoord[b * 9 + 0 * 3 + c] - cx;
            float dy = vcoord[b * 9 + 1 * 3 + c] - cy;
            float dz = vcoord[b * 9 + 2 * 3 + c] - cz;
            unsigned short* pad = &e_buf[(3 * tid + c) * ESTR + 128];
            pad[0] = f2bf(dx);            // diff used only for trans (tiny terms)
            pad[1] = f2bf(dy);
            pad[2] = f2bf(dz);
            sradial[tid][c] = sqrtf(dx * dx + dy * dy + dz * dz);  // fp32: feeds MLP
        }
    }
    __syncthreads();
    const int nseg = snseg;   // block-uniform

    // ---- GEMM1: P[64,128] = node_feat_tile @ We1_top; wave w -> nodes 16w..16w+15
    f32x4 acc1[8] = {};
    {
        const float* arow = node_feat + (size_t)(node0 + wave * 16 + lrow) * 128;
        for (int ks = 0; ks < 4; ++ks) {
            f32x4 x0 = *(const f32x4*)(arow + ks * 32 + lkb);
            f32x4 x1 = *(const f32x4*)(arow + ks * 32 + lkb + 4);
            short8 af;
            af[0] = (short)f2bf(x0[0]); af[1] = (short)f2bf(x0[1]);
            af[2] = (short)f2bf(x0[2]); af[3] = (short)f2bf(x0[3]);
            af[4] = (short)f2bf(x1[0]); af[5] = (short)f2bf(x1[1]);
            af[6] = (short)f2bf(x1[2]); af[7] = (short)f2bf(x1[3]);
            for (int ct = 0; ct < 8; ++ct) {
                short8 bfg = *(const short8*)(w1r + ((ct * 4 + ks) * 64 + lane) * 8);
                acc1[ct] = MFMA_16x16x32(af, bfg, acc1[ct]);
            }
        }
    }
    // Epilogue 1: E1[(3n+c), h] = silu(P + Q[b,c,h] + radial*wlast[h] + be1[h])
    for (int ct = 0; ct < 8; ++ct) {
        int h = ct * 16 + lrow;
        float wl = wlast[h];
        float bb = be1f[h];
        for (int r = 0; r < 4; ++r) {
            int nl = wave * 16 + rq + r;
            int b  = sbatch[nl];
            float p = acc1[ct][r] + bb;
            for (int c = 0; c < 3; ++c) {
                float x = p + Q[(b * 3 + c) * 128 + h] + sradial[nl][c] * wl;
                e_buf[(3 * nl + c) * ESTR + h] = f2bf(silu_f(x));
            }
        }
    }

    // ---- GEMM2+GEMM3, i-split: one 16-row chunk at a time (32-reg acc) ----
    for (int i = 0; i < 3; ++i) {
        const int rowbase = (wave * 3 + i) * 16;

        // GEMM2_i: M = silu(E1 @ We2 + be2)
        f32x4 acc[8] = {};
        for (int ks = 0; ks < 4; ++ks) {
            short8 af = ld_frag8(&e_buf[(rowbase + lrow) * ESTR + ks * 32 + lkb]);
            for (int ct = 0; ct < 8; ++ct) {
                short8 bfg = *(const short8*)(w2r + ((ct * 4 + ks) * 64 + lane) * 8);
                acc[ct] = MFMA_16x16x32(af, bfg, acc[ct]);
            }
        }
        // Epilogue 2_i: write M (bf16) + fast-path segment-sum (through bf16 to
        // match the rounded values the slow path sums — r2 numerics)
        for (int ct = 0; ct < 8; ++ct) {
            int h = ct * 16 + lrow;
            float bb = be2f[h];
            float psum = 0.0f;
            for (int r = 0; r < 4; ++r) {
                int row = rowbase + rq + r;
                unsigned short us = f2bf(silu_f(acc[ct][r] + bb));
                e_buf[row * ESTR + h] = us;
                psum += bf2f(us);
            }
            if (nseg == 1) {
                psum += __shfl_xor(psum, 16, 64);
                psum += __shfl_xor(psum, 32, 64);
                if (lane < 16)
                    atomicAdd(&sagg[i * 128 + ct * 16 + lane], psum);
            }
        }

        // GEMM3_i: SH = silu(M @ Wc1 + bc1); s = SH . Wc2 (never materialized)
        f32x4 acc3[8] = {};
        for (int ks = 0; ks < 4; ++ks) {
            short8 af = ld_frag8(&e_buf[(rowbase + lrow) * ESTR + ks * 32 + lkb]);
            for (int ct = 0; ct < 8; ++ct) {
                short8 bfg = *(const short8*)(wc1r + ((ct * 4 + ks) * 64 + lane) * 8);
                acc3[ct] = MFMA_16x16x32(af, bfg, acc3[ct]);
            }
        }
        float p0 = 0.f, p1 = 0.f, p2 = 0.f, p3 = 0.f;
        for (int ct = 0; ct < 8; ++ct) {
            int h = ct * 16 + lrow;
            float bb = bc1f[h];
            float w2 = wc2f[h];
            p0 += silu_f(acc3[ct][0] + bb) * w2;
            p1 += silu_f(acc3[ct][1] + bb) * w2;
            p2 += silu_f(acc3[ct][2] + bb) * w2;
            p3 += silu_f(acc3[ct][3] + bb) * w2;
        }
        for (int off = 1; off < 16; off <<= 1) {   // reduce over the 16 col-lanes
            p0 += __shfl_xor(p0, off, 64);
            p1 += __shfl_xor(p1, off, 64);
            p2 += __shfl_xor(p2, off, 64);
            p3 += __shfl_xor(p3, off, 64);
        }
        if (lrow == 0) {
            int rbase = rowbase + rq;
            s_s[rbase + 0] = p0;
            s_s[rbase + 1] = p1;
            s_s[rbase + 2] = p2;
            s_s[rbase + 3] = p3;
        }
    }
    __syncthreads();

    // ---- Reduce to global ----
    if (nseg == 1) {
        int b = sseg_b[0];
        for (int idx = tid; idx < NCH * HD; idx += 256)
            atomicAdd(&aggsum[b * NCH * HD + idx], sagg[idx]);
    } else {
        for (int sg = 0; sg < nseg; ++sg) {
            int s0 = sseg_start[sg], s1 = sseg_start[sg + 1], b = sseg_b[sg];
            for (int idx = tid; idx < NCH * HD; idx += 256) {
                int c = idx >> 7, h = idx & 127;
                float sum = 0.f;
                for (int ii = s0; ii < s1; ++ii)
                    sum += bf2f(e_buf[(3 * ii + c) * ESTR + h]);
                atomicAdd(&aggsum[(b * 3 + c) * 128 + h], sum);
            }
        }
    }
    for (int sg = 0; sg < nseg; ++sg) {
        int s0 = sseg_start[sg], s1 = sseg_start[sg + 1], b = sseg_b[sg];
        if (tid < 9) {
            int d = tid / 3, c = tid % 3;
            float sum = 0.f;
            for (int ii = s0; ii < s1; ++ii)
                sum += bf2f(e_buf[(3 * ii + c) * ESTR + 128 + d]) * s_s[3 * ii + c];
            atomicAdd(&transsum[b * 9 + d * 3 + c], sum);
        }
        if (tid == 0) atomicAdd(&cnt[b], (float)(s1 - s0));
    }
}

// ---------------------------------------------------------------------------
// Finalize: one block per (b,c) row. Means, node model, residuals, outputs.
// ---------------------------------------------------------------------------
__global__ void finalize_kernel(const float* __restrict__ vnf,
                                const float* __restrict__ vcoord,
                                const float* __restrict__ Wn1,
                                const float* __restrict__ bn1,
                                const float* __restrict__ Wn2,
                                const float* __restrict__ bn2,
                                const float* __restrict__ aggsum,
                                const float* __restrict__ transsum,
                                const float* __restrict__ cnt,
                                float* __restrict__ out) {
    int b = blockIdx.x / NCH;
    int c = blockIdx.x % NCH;
    int j = threadIdx.x;   // 0..127
    __shared__ float nin[256];
    __shared__ float h1[128];
    float count = fmaxf(cnt[b], 1.0f);
    nin[j]       = vnf[(b * 128 + j) * 3 + c];
    nin[128 + j] = aggsum[(b * 3 + c) * 128 + j] / count;
    __syncthreads();
    float x = bn1[j];
    for (int k = 0; k < 256; ++k)
        x += nin[k] * Wn1[k * 128 + j];
    h1[j] = silu_f(x);
    __syncthreads();
    float y = bn2[j];
    for (int k = 0; k < 128; ++k)
        y += h1[k] * Wn2[k * 128 + j];
    out[(b * 128 + j) * 3 + c] = vnf[(b * 128 + j) * 3 + c] + y;
    if (c == 0 && j < 9) {
        out[NGRAPH * 128 * 3 + b * 9 + j] =
            vcoord[b * 9 + j] + transsum[b * 9 + j] / count;
    }
}

// ---------------------------------------------------------------------------
extern "C" void kernel_launch(void* const* d_in, const int* in_sizes, int n_in,
                              void* d_out, int out_size, void* d_ws, size_t ws_size,
                              hipStream_t stream) {
    const float* node_feat = (const float*)d_in[0];
    const float* coord     = (const float*)d_in[1];
    const float* vnf       = (const float*)d_in[2];
    const float* vcoord    = (const float*)d_in[3];
    const int*   batch     = (const int*)d_in[4];
    const float* We1 = (const float*)d_in[5];
    const float* be1 = (const float*)d_in[6];
    const float* We2 = (const float*)d_in[7];
    const float* be2 = (const float*)d_in[8];
    const float* Wc1 = (const float*)d_in[9];
    const float* bc1 = (const float*)d_in[10];
    const float* Wc2 = (const float*)d_in[11];
    const float* Wn1 = (const float*)d_in[12];
    const float* bn1 = (const float*)d_in[13];
    const float* Wn2 = (const float*)d_in[14];
    const float* bn2 = (const float*)d_in[15];

    char* ws = (char*)d_ws;
    float*          aggsum   = (float*)(ws + 0);          // 153600
    float*          transsum = (float*)(ws + 153600);     // 3600
    float*          cntp     = (float*)(ws + 157200);     // 400
    float*          Q        = (float*)(ws + 157600);     // 153600
    unsigned short* w1r      = (unsigned short*)(ws + 311200); // 32768
    unsigned short* w2r      = (unsigned short*)(ws + 343968); // 32768
    unsigned short* wc1r     = (unsigned short*)(ws + 376736); // 32768
    float*          wlast    = (float*)(ws + 409504);
    float*          be1f     = (float*)(ws + 410016);
    float*          be2f     = (float*)(ws + 410528);
    float*          bc1f     = (float*)(ws + 411040);
    float*          wc2f     = (float*)(ws + 411552);

    (void)hipMemsetAsync(d_ws, 0, 157600, stream);  // zero accumulators each call

    repack_kernel<<<(3 * 16384 + 255) / 256, 256, 0, stream>>>(
        We1, We2, Wc1, be1, be2, bc1, Wc2,
        w1r, w2r, wc1r, wlast, be1f, be2f, bc1f, wc2f);

    q_kernel<<<NGRAPH * NCH, 128, 0, stream>>>(vnf, We1, Q);

    egcl_main<<<NNODES / BN, 256, 0, stream>>>(
        node_feat, coord, vcoord, batch, w1r, w2r, wc1r, Q,
        wlast, be1f, be2f, bc1f, wc2f, aggsum, transsum, cntp);

    finalize_kernel<<<NGRAPH * NCH, 128, 0, stream>>>(
        vnf, vcoord, Wn1, bn1, Wn2, bn2, aggsum, transsum, cntp,
        (float*)d_out);
}

// Round 5
// 365.607 us; speedup vs baseline: 2.0012x; 2.0012x over previous
//
#include <hip/hip_runtime.h>
#include <hip/hip_bf16.h>
#include <math.h>

// Problem constants
#define NNODES 200000
#define NGRAPH 100
#define HD     128      // H == NF == 128
#define NCH    3        // virtual channels
#define BN     64       // nodes per block
#define EROWS  (BN*NCH) // 192 e-rows per block
#define ESTR   136      // row stride 272B: 16B-aligned (ds_read_b128), 2-way banks (free)

// e_buf row layout: row' = c*64 + nl  (channel-major). Channel boundaries at
// multiples of 16 -> every 16-row MFMA chunk is channel-pure (chunk>>2 = c).
// Wave w owns chunks {w, w+4, w+8} = exactly the rows its epilogue-1 wrote
// (nodes 16w..16w+15, all 3 channels) -> GEMM1->2->3 need NO barriers.

typedef short short8 __attribute__((ext_vector_type(8)));
typedef float f32x4  __attribute__((ext_vector_type(4)));

#define MFMA_16x16x32(a,b,c) __builtin_amdgcn_mfma_f32_16x16x32_bf16((a),(b),(c),0,0,0)

__device__ __forceinline__ float bf2f(unsigned short u) {
    return __uint_as_float(((unsigned int)u) << 16);
}
// round-half-up: 2 VALU ops; ties (lower bits == 0x8000) are measure-zero for
// arithmetic-derived floats, so error bound == RNE (<= 0.5 ulp).
__device__ __forceinline__ unsigned short f2bf(float f) {
    return (unsigned short)((__float_as_uint(f) + 0x8000u) >> 16);
}
__device__ __forceinline__ float silu_f(float x) {
    return x * __builtin_amdgcn_rcpf(1.0f + __expf(-x));
}

// ---------------------------------------------------------------------------
// prep: blocks [0,192) repack We1[0:128]/We2/Wc1 into bf16 MFMA B-frag order
//   rep[((ct*4+ks)*64 + lane)*8 + j] = bf16(W[ks*32+(lane>>4)*8+j][ct*16+(lane&15)])
// blocks [192,492) compute Q[b,c,h] = sum_k vnf[b,k,c]*We1[128+k,h]
// ---------------------------------------------------------------------------
__global__ void prep_kernel(const float* __restrict__ We1,
                            const float* __restrict__ We2,
                            const float* __restrict__ Wc1,
                            const float* __restrict__ be1,
                            const float* __restrict__ be2,
                            const float* __restrict__ bc1,
                            const float* __restrict__ Wc2,
                            const float* __restrict__ vnf,
                            unsigned short* __restrict__ w1r,
                            unsigned short* __restrict__ w2r,
                            unsigned short* __restrict__ wc1r,
                            float* __restrict__ Q,
                            float* __restrict__ wlast,
                            float* __restrict__ be1f,
                            float* __restrict__ be2f,
                            float* __restrict__ bc1f,
                            float* __restrict__ wc2f) {
    int bid = blockIdx.x;
    if (bid < 192) {
        int t = bid * 256 + threadIdx.x;   // < 49152 = 3*16384
        int m  = t / 16384;
        int e  = t % 16384;
        int j  = e & 7;
        int l  = (e >> 3) & 63;
        int ks = (e >> 9) & 3;
        int ct = e >> 11;
        int row = ks * 32 + (l >> 4) * 8 + j;
        int col = ct * 16 + (l & 15);
        const float*    src = (m == 0) ? We1 : ((m == 1) ? We2 : Wc1);
        unsigned short* dst = (m == 0) ? w1r : ((m == 1) ? w2r : wc1r);
        dst[e] = f2bf(src[row * 128 + col]);
        if (t < 128) {
            wlast[t] = We1[256 * 128 + t];
            be1f[t]  = be1[t];
            be2f[t]  = be2[t];
            bc1f[t]  = bc1[t];
            wc2f[t]  = Wc2[t];
        }
    } else {
        int bc = bid - 192;                // 0..299
        int b = bc / NCH, c = bc % NCH;
        int t = threadIdx.x;
        __shared__ float v[128];
        if (t < 128) v[t] = vnf[(b * 128 + t) * 3 + c];
        __syncthreads();
        if (t < 128) {
            float s = 0.0f;
            for (int k = 0; k < 128; ++k)
                s += v[k] * We1[(128 + k) * 128 + t];
            Q[(b * 3 + c) * 128 + t] = s;
        }
    }
}

// ---------------------------------------------------------------------------
// Main fused kernel: 64 nodes/block, 256 threads (4 waves), 3125 blocks.
// launch_bounds(256,2): 256-reg unified budget -> NO spills (r3/r4 lesson:
// (256,3)'s 170-reg budget spills ~1.5 GB of scratch traffic).
// ---------------------------------------------------------------------------
__global__ __launch_bounds__(256, 2) void egcl_main(
    const float* __restrict__ node_feat,   // [N,128]
    const float* __restrict__ coord,       // [N,3]
    const float* __restrict__ vcoord,      // [B,3,C]
    const int*   __restrict__ batch,       // [N] sorted
    const unsigned short* __restrict__ w1r,
    const unsigned short* __restrict__ w2r,
    const unsigned short* __restrict__ wc1r,
    const float* __restrict__ Q,           // [B,C,H]
    const float* __restrict__ wlast,
    const float* __restrict__ be1f,
    const float* __restrict__ be2f,
    const float* __restrict__ bc1f,
    const float* __restrict__ wc2f,
    float* __restrict__ aggsum,            // [B,C,H]
    float* __restrict__ transsum,          // [B,3,C]
    float* __restrict__ cnt)               // [B]
{
    __shared__ __align__(16) unsigned short e_buf[EROWS * ESTR]; // 52224 B
    __shared__ float sdiff[BN][3][3];       // 2304 B (fp32 — r2 numerics)
    __shared__ float sradial[BN][3];        // 768 B
    __shared__ float s_s[EROWS];            // 768 B  (indexed by row' = c*64+nl)
    __shared__ float sagg[NCH * HD];        // 1536 B (fast-path per-CHANNEL sums)
    __shared__ unsigned short sbatch[BN];
    __shared__ unsigned short sseg_start[BN + 1];
    __shared__ unsigned short sseg_b[BN];
    __shared__ int snseg;

    const int tid   = threadIdx.x;
    const int wave  = tid >> 6;
    const int lane  = tid & 63;
    const int lrow  = lane & 15;           // MFMA row (A) / col (D) index
    const int lkb   = (lane >> 4) * 8;     // k-offset base within 32-wide K step
    const int rq    = (lane >> 4) * 4;     // D row-group base
    const int node0 = blockIdx.x * BN;

    // ---- Phase 0 ----
    for (int k = tid; k < NCH * HD; k += 256) sagg[k] = 0.0f;
    if (tid < BN) {  // wave 0
        int n = node0 + tid;
        int b = batch[n];
        sbatch[tid] = (unsigned short)b;
        int prev = (tid > 0) ? batch[n - 1] : -1;
        unsigned long long mask = __ballot(b != prev);
        int ns = __popcll(mask);
        if (b != prev) {
            int idx = __popcll(mask & ((1ull << tid) - 1ull));
            sseg_start[idx] = (unsigned short)tid;
            sseg_b[idx]     = (unsigned short)b;
        }
        if (tid == 0) { sseg_start[ns] = BN; snseg = ns; }
        float cx = coord[n * 3 + 0];
        float cy = coord[n * 3 + 1];
        float cz = coord[n * 3 + 2];
        for (int c = 0; c < 3; ++c) {
            float dx = vcoord[b * 9 + 0 * 3 + c] - cx;
            float dy = vcoord[b * 9 + 1 * 3 + c] - cy;
            float dz = vcoord[b * 9 + 2 * 3 + c] - cz;
            sdiff[tid][0][c] = dx;
            sdiff[tid][1][c] = dy;
            sdiff[tid][2][c] = dz;
            sradial[tid][c] = sqrtf(dx * dx + dy * dy + dz * dz);
        }
    }
    __syncthreads();
    const int nseg = snseg;   // block-uniform

    // ---- GEMM1: P[64,128] = node_feat_tile @ We1_top; wave w -> nodes 16w..16w+15
    f32x4 acc1[8] = {};
    {
        const float* arow = node_feat + (size_t)(node0 + wave * 16 + lrow) * 128;
        for (int ks = 0; ks < 4; ++ks) {
            f32x4 x0 = *(const f32x4*)(arow + ks * 32 + lkb);
            f32x4 x1 = *(const f32x4*)(arow + ks * 32 + lkb + 4);
            short8 af;
            af[0] = (short)f2bf(x0[0]); af[1] = (short)f2bf(x0[1]);
            af[2] = (short)f2bf(x0[2]); af[3] = (short)f2bf(x0[3]);
            af[4] = (short)f2bf(x1[0]); af[5] = (short)f2bf(x1[1]);
            af[6] = (short)f2bf(x1[2]); af[7] = (short)f2bf(x1[3]);
            for (int ct = 0; ct < 8; ++ct) {
                short8 bfg = *(const short8*)(w1r + ((ct * 4 + ks) * 64 + lane) * 8);
                acc1[ct] = MFMA_16x16x32(af, bfg, acc1[ct]);
            }
        }
    }
    // Epilogue 1: E1[c*64+nl, h] = silu(P + Q[b,c,h] + radial*wlast[h] + be1[h])
    for (int ct = 0; ct < 8; ++ct) {
        int h = ct * 16 + lrow;
        float wl = wlast[h];
        float bb = be1f[h];
        for (int r = 0; r < 4; ++r) {
            int nl = wave * 16 + rq + r;
            int b  = sbatch[nl];
            float p = acc1[ct][r] + bb;
            for (int c = 0; c < 3; ++c) {
                float x = p + Q[(b * 3 + c) * 128 + h] + sradial[nl][c] * wl;
                e_buf[(c * 64 + nl) * ESTR + h] = f2bf(silu_f(x));
            }
        }
    }
    // (no barrier: wave w's chunks {w, w+4, w+8} are exactly the rows it wrote)

    // ---- GEMM2: M = silu(E1 @ We2 + be2); wave w -> chunks w+4j (channel j) ----
    f32x4 acc2[3][8] = {};
    for (int ks = 0; ks < 4; ++ks) {
        short8 af[3];
        for (int j = 0; j < 3; ++j)
            af[j] = *(const short8*)(&e_buf[(j * 64 + wave * 16 + lrow) * ESTR +
                                            ks * 32 + lkb]);
        for (int ct = 0; ct < 8; ++ct) {
            short8 bfg = *(const short8*)(w2r + ((ct * 4 + ks) * 64 + lane) * 8);
            for (int j = 0; j < 3; ++j)
                acc2[j][ct] = MFMA_16x16x32(af[j], bfg, acc2[j][ct]);
        }
    }
    // Epilogue 2: write M (bf16) + fast-path per-channel register segment-sum
    for (int j = 0; j < 3; ++j) {
        for (int ct = 0; ct < 8; ++ct) {
            int h = ct * 16 + lrow;
            float bb = be2f[h];
            float psum = 0.0f;
            for (int r = 0; r < 4; ++r) {
                int row = j * 64 + wave * 16 + rq + r;
                unsigned short us = f2bf(silu_f(acc2[j][ct][r] + bb));
                e_buf[row * ESTR + h] = us;
                psum += bf2f(us);
            }
            if (nseg == 1) {
                psum += __shfl_xor(psum, 16, 64);
                psum += __shfl_xor(psum, 32, 64);
                if (lane < 16)
                    atomicAdd(&sagg[j * 128 + ct * 16 + lane], psum);
            }
        }
    }

    // ---- GEMM3: SH = silu(M @ Wc1 + bc1); s = SH . Wc2 (never materialized) ----
    f32x4 acc3[3][8] = {};
    for (int ks = 0; ks < 4; ++ks) {
        short8 af[3];
        for (int j = 0; j < 3; ++j)
            af[j] = *(const short8*)(&e_buf[(j * 64 + wave * 16 + lrow) * ESTR +
                                            ks * 32 + lkb]);
        for (int ct = 0; ct < 8; ++ct) {
            short8 bfg = *(const short8*)(wc1r + ((ct * 4 + ks) * 64 + lane) * 8);
            for (int j = 0; j < 3; ++j)
                acc3[j][ct] = MFMA_16x16x32(af[j], bfg, acc3[j][ct]);
        }
    }
    for (int j = 0; j < 3; ++j) {
        float p0 = 0.f, p1 = 0.f, p2 = 0.f, p3 = 0.f;
        for (int ct = 0; ct < 8; ++ct) {
            int h = ct * 16 + lrow;
            float bb = bc1f[h];
            float w2 = wc2f[h];
            p0 += silu_f(acc3[j][ct][0] + bb) * w2;
            p1 += silu_f(acc3[j][ct][1] + bb) * w2;
            p2 += silu_f(acc3[j][ct][2] + bb) * w2;
            p3 += silu_f(acc3[j][ct][3] + bb) * w2;
        }
        for (int off = 1; off < 16; off <<= 1) {
            p0 += __shfl_xor(p0, off, 64);
            p1 += __shfl_xor(p1, off, 64);
            p2 += __shfl_xor(p2, off, 64);
            p3 += __shfl_xor(p3, off, 64);
        }
        if (lrow == 0) {
            int rbase = j * 64 + wave * 16 + rq;
            s_s[rbase + 0] = p0;
            s_s[rbase + 1] = p1;
            s_s[rbase + 2] = p2;
            s_s[rbase + 3] = p3;
        }
    }
    __syncthreads();

    // ---- Reduce to global ----
    if (nseg == 1) {
        int b = sseg_b[0];
        for (int idx = tid; idx < NCH * HD; idx += 256)
            atomicAdd(&aggsum[b * NCH * HD + idx], sagg[idx]);
    } else {
        for (int sg = 0; sg < nseg; ++sg) {
            int s0 = sseg_start[sg], s1 = sseg_start[sg + 1], b = sseg_b[sg];
            for (int idx = tid; idx < NCH * HD; idx += 256) {
                int c = idx >> 7, h = idx & 127;
                float sum = 0.f;
                for (int ii = s0; ii < s1; ++ii)
                    sum += bf2f(e_buf[(c * 64 + ii) * ESTR + h]);
                atomicAdd(&aggsum[(b * 3 + c) * 128 + h], sum);
            }
        }
    }
    for (int sg = 0; sg < nseg; ++sg) {
        int s0 = sseg_start[sg], s1 = sseg_start[sg + 1], b = sseg_b[sg];
        if (tid < 9) {
            int d = tid / 3, c = tid % 3;
            float sum = 0.f;
            for (int ii = s0; ii < s1; ++ii)
                sum += sdiff[ii][d][c] * s_s[c * 64 + ii];
            atomicAdd(&transsum[b * 9 + d * 3 + c], sum);
        }
        if (tid == 0) atomicAdd(&cnt[b], (float)(s1 - s0));
    }
}

// ---------------------------------------------------------------------------
// Finalize: one block per (b,c) row. Means, node model, residuals, outputs.
// ---------------------------------------------------------------------------
__global__ void finalize_kernel(const float* __restrict__ vnf,
                                const float* __restrict__ vcoord,
                                const float* __restrict__ Wn1,
                                const float* __restrict__ bn1,
                                const float* __restrict__ Wn2,
                                const float* __restrict__ bn2,
                                const float* __restrict__ aggsum,
                                const float* __restrict__ transsum,
                                const float* __restrict__ cnt,
                                float* __restrict__ out) {
    int b = blockIdx.x / NCH;
    int c = blockIdx.x % NCH;
    int j = threadIdx.x;   // 0..127
    __shared__ float nin[256];
    __shared__ float h1[128];
    float count = fmaxf(cnt[b], 1.0f);
    nin[j]       = vnf[(b * 128 + j) * 3 + c];
    nin[128 + j] = aggsum[(b * 3 + c) * 128 + j] / count;
    __syncthreads();
    float x = bn1[j];
    for (int k = 0; k < 256; ++k)
        x += nin[k] * Wn1[k * 128 + j];
    h1[j] = silu_f(x);
    __syncthreads();
    float y = bn2[j];
    for (int k = 0; k < 128; ++k)
        y += h1[k] * Wn2[k * 128 + j];
    out[(b * 128 + j) * 3 + c] = vnf[(b * 128 + j) * 3 + c] + y;
    if (c == 0 && j < 9) {
        out[NGRAPH * 128 * 3 + b * 9 + j] =
            vcoord[b * 9 + j] + transsum[b * 9 + j] / count;
    }
}

// ---------------------------------------------------------------------------
extern "C" void kernel_launch(void* const* d_in, const int* in_sizes, int n_in,
                              void* d_out, int out_size, void* d_ws, size_t ws_size,
                              hipStream_t stream) {
    const float* node_feat = (const float*)d_in[0];
    const float* coord     = (const float*)d_in[1];
    const float* vnf       = (const float*)d_in[2];
    const float* vcoord    = (const float*)d_in[3];
    const int*   batch     = (const int*)d_in[4];
    const float* We1 = (const float*)d_in[5];
    const float* be1 = (const float*)d_in[6];
    const float* We2 = (const float*)d_in[7];
    const float* be2 = (const float*)d_in[8];
    const float* Wc1 = (const float*)d_in[9];
    const float* bc1 = (const float*)d_in[10];
    const float* Wc2 = (const float*)d_in[11];
    const float* Wn1 = (const float*)d_in[12];
    const float* bn1 = (const float*)d_in[13];
    const float* Wn2 = (const float*)d_in[14];
    const float* bn2 = (const float*)d_in[15];

    char* ws = (char*)d_ws;
    float*          aggsum   = (float*)(ws + 0);          // 153600
    float*          transsum = (float*)(ws + 153600);     // 3600
    float*          cntp     = (float*)(ws + 157200);     // 400
    float*          Q        = (float*)(ws + 157600);     // 153600
    unsigned short* w1r      = (unsigned short*)(ws + 311200); // 32768
    unsigned short* w2r      = (unsigned short*)(ws + 343968); // 32768
    unsigned short* wc1r     = (unsigned short*)(ws + 376736); // 32768
    float*          wlast    = (float*)(ws + 409504);
    float*          be1f     = (float*)(ws + 410016);
    float*          be2f     = (float*)(ws + 410528);
    float*          bc1f     = (float*)(ws + 411040);
    float*          wc2f     = (float*)(ws + 411552);

    (void)hipMemsetAsync(d_ws, 0, 157600, stream);  // zero accumulators each call

    prep_kernel<<<192 + NGRAPH * NCH, 256, 0, stream>>>(
        We1, We2, Wc1, be1, be2, bc1, Wc2, vnf,
        w1r, w2r, wc1r, Q, wlast, be1f, be2f, bc1f, wc2f);

    egcl_main<<<NNODES / BN, 256, 0, stream>>>(
        node_feat, coord, vcoord, batch, w1r, w2r, wc1r, Q,
        wlast, be1f, be2f, bc1f, wc2f, aggsum, transsum, cntp);

    finalize_kernel<<<NGRAPH * NCH, 128, 0, stream>>>(
        vnf, vcoord, Wn1, bn1, Wn2, bn2, aggsum, transsum, cntp,
        (float*)d_out);
}

// Round 6
// 363.430 us; speedup vs baseline: 2.0132x; 1.0060x over previous
//
#include <hip/hip_runtime.h>
#include <hip/hip_bf16.h>
#include <math.h>

// Problem constants
#define NNODES 200000
#define NGRAPH 100
#define HD     128      // H == NF == 128
#define NCH    3        // virtual channels
#define BN     64       // nodes per block
#define EROWS  (BN*NCH) // 192 e-rows per block
#define ESTR   136      // 128 data + 8 pad cols; row stride 272B (16B aligned)
// Pad cols per row (row' = c*64+nl): [128..129]=fp32 dx, [130..131]=fp32 dy,
// [132..133]=fp32 dz, [134..135]=fp32 radial  (exact fp32, 16B aligned block).
// e_buf row layout: row' = c*64 + nl (channel-major) -> every 16-row MFMA chunk
// is channel-pure; wave w owns chunks {w, w+4, w+8} = rows its epilogue-1 wrote
// -> GEMM1->2->3 need NO barriers.

typedef short short8 __attribute__((ext_vector_type(8)));
typedef float f32x4  __attribute__((ext_vector_type(4)));

#define MFMA_16x16x32(a,b,c) __builtin_amdgcn_mfma_f32_16x16x32_bf16((a),(b),(c),0,0,0)

__device__ __forceinline__ float bf2f(unsigned short u) {
    return __uint_as_float(((unsigned int)u) << 16);
}
// round-half-up: 2 VALU ops; ties measure-zero for arithmetic-derived floats.
__device__ __forceinline__ unsigned short f2bf(float f) {
    return (unsigned short)((__float_as_uint(f) + 0x8000u) >> 16);
}
__device__ __forceinline__ float silu_f(float x) {
    return x * __builtin_amdgcn_rcpf(1.0f + __expf(-x));
}

// ---------------------------------------------------------------------------
// prep: blocks [0,192) repack We1[0:128]/We2/Wc1 into bf16 MFMA B-frag order
//   rep[((ct*4+ks)*64 + lane)*8 + j] = bf16(W[ks*32+(lane>>4)*8+j][ct*16+(lane&15)])
// blocks [192,492) compute Q[b,c,h] = sum_k vnf[b,k,c]*We1[128+k,h]
// ---------------------------------------------------------------------------
__global__ void prep_kernel(const float* __restrict__ We1,
                            const float* __restrict__ We2,
                            const float* __restrict__ Wc1,
                            const float* __restrict__ be1,
                            const float* __restrict__ be2,
                            const float* __restrict__ bc1,
                            const float* __restrict__ Wc2,
                            const float* __restrict__ vnf,
                            unsigned short* __restrict__ w1r,
                            unsigned short* __restrict__ w2r,
                            unsigned short* __restrict__ wc1r,
                            float* __restrict__ Q,
                            float* __restrict__ wlast,
                            float* __restrict__ be1f,
                            float* __restrict__ be2f,
                            float* __restrict__ bc1f,
                            float* __restrict__ wc2f) {
    int bid = blockIdx.x;
    if (bid < 192) {
        int t = bid * 256 + threadIdx.x;   // < 49152 = 3*16384
        int m  = t / 16384;
        int e  = t % 16384;
        int j  = e & 7;
        int l  = (e >> 3) & 63;
        int ks = (e >> 9) & 3;
        int ct = e >> 11;
        int row = ks * 32 + (l >> 4) * 8 + j;
        int col = ct * 16 + (l & 15);
        const float*    src = (m == 0) ? We1 : ((m == 1) ? We2 : Wc1);
        unsigned short* dst = (m == 0) ? w1r : ((m == 1) ? w2r : wc1r);
        dst[e] = f2bf(src[row * 128 + col]);
        if (t < 128) {
            wlast[t] = We1[256 * 128 + t];
            be1f[t]  = be1[t];
            be2f[t]  = be2[t];
            bc1f[t]  = bc1[t];
            wc2f[t]  = Wc2[t];
        }
    } else {
        int bc = bid - 192;                // 0..299
        int b = bc / NCH, c = bc % NCH;
        int t = threadIdx.x;
        __shared__ float v[128];
        if (t < 128) v[t] = vnf[(b * 128 + t) * 3 + c];
        __syncthreads();
        if (t < 128) {
            float s = 0.0f;
            for (int k = 0; k < 128; ++k)
                s += v[k] * We1[(128 + k) * 128 + t];
            Q[(b * 3 + c) * 128 + t] = s;
        }
    }
}

// ---------------------------------------------------------------------------
// Main fused kernel: 64 nodes/block, 256 threads (4 waves), 3125 blocks.
// LDS ~53.4 KB -> 3 blocks/CU (limit 54613 B/block at 3/CU).
// launch_bounds(256,2): 256-reg budget -> no spills (r3/r4 lesson); any
// VGPR_Count <= 170 still permits 12 waves/CU (3 blocks).
// ---------------------------------------------------------------------------
__global__ __launch_bounds__(256, 2) void egcl_main(
    const float* __restrict__ node_feat,   // [N,128]
    const float* __restrict__ coord,       // [N,3]
    const float* __restrict__ vcoord,      // [B,3,C]
    const int*   __restrict__ batch,       // [N] sorted
    const unsigned short* __restrict__ w1r,
    const unsigned short* __restrict__ w2r,
    const unsigned short* __restrict__ wc1r,
    const float* __restrict__ Q,           // [B,C,H]
    const float* __restrict__ wlast,
    const float* __restrict__ be1f,
    const float* __restrict__ be2f,
    const float* __restrict__ bc1f,
    const float* __restrict__ wc2f,
    float* __restrict__ aggsum,            // [B,C,H]
    float* __restrict__ transsum,          // [B,3,C]
    float* __restrict__ cnt)               // [B]
{
    __shared__ __align__(16) unsigned short e_buf[EROWS * ESTR]; // 52224 B
    __shared__ float s_s[EROWS];            // 768 B (indexed by row' = c*64+nl)
    __shared__ unsigned short sbatch[BN];
    __shared__ unsigned short sseg_start[BN + 1];
    __shared__ unsigned short sseg_b[BN];
    __shared__ int snseg;

    const int tid   = threadIdx.x;
    const int wave  = tid >> 6;
    const int lane  = tid & 63;
    const int lrow  = lane & 15;           // MFMA row (A) / col (D) index
    const int lkb   = (lane >> 4) * 8;     // k-offset base within 32-wide K step
    const int rq    = (lane >> 4) * 4;     // D row-group base
    const int node0 = blockIdx.x * BN;

    // ---- Phase 0 ----
    if (tid < BN) {  // wave 0
        int n = node0 + tid;
        int b = batch[n];
        sbatch[tid] = (unsigned short)b;
        int prev = (tid > 0) ? batch[n - 1] : -1;
        unsigned long long mask = __ballot(b != prev);
        int ns = __popcll(mask);
        if (b != prev) {
            int idx = __popcll(mask & ((1ull << tid) - 1ull));
            sseg_start[idx] = (unsigned short)tid;
            sseg_b[idx]     = (unsigned short)b;
        }
        if (tid == 0) { sseg_start[ns] = BN; snseg = ns; }
        float cx = coord[n * 3 + 0];
        float cy = coord[n * 3 + 1];
        float cz = coord[n * 3 + 2];
        for (int c = 0; c < 3; ++c) {
            float dx = vcoord[b * 9 + 0 * 3 + c] - cx;
            float dy = vcoord[b * 9 + 1 * 3 + c] - cy;
            float dz = vcoord[b * 9 + 2 * 3 + c] - cz;
            f32x4 pad;
            pad[0] = dx; pad[1] = dy; pad[2] = dz;
            pad[3] = sqrtf(dx * dx + dy * dy + dz * dz);
            *(f32x4*)&e_buf[(c * 64 + tid) * ESTR + 128] = pad;  // 16B aligned
        }
    }
    __syncthreads();
    const int nseg = snseg;   // block-uniform

    // ---- GEMM1: P[64,128] = node_feat_tile @ We1_top; wave w -> nodes 16w..16w+15
    f32x4 acc1[8] = {};
    {
        const float* arow = node_feat + (size_t)(node0 + wave * 16 + lrow) * 128;
        for (int ks = 0; ks < 4; ++ks) {
            f32x4 x0 = *(const f32x4*)(arow + ks * 32 + lkb);
            f32x4 x1 = *(const f32x4*)(arow + ks * 32 + lkb + 4);
            short8 af;
            af[0] = (short)f2bf(x0[0]); af[1] = (short)f2bf(x0[1]);
            af[2] = (short)f2bf(x0[2]); af[3] = (short)f2bf(x0[3]);
            af[4] = (short)f2bf(x1[0]); af[5] = (short)f2bf(x1[1]);
            af[6] = (short)f2bf(x1[2]); af[7] = (short)f2bf(x1[3]);
            for (int ct = 0; ct < 8; ++ct) {
                short8 bfg = *(const short8*)(w1r + ((ct * 4 + ks) * 64 + lane) * 8);
                acc1[ct] = MFMA_16x16x32(af, bfg, acc1[ct]);
            }
        }
    }
    // Epilogue 1: E1[c*64+nl, h] = silu(P + Q[b,c,h] + radial*wlast[h] + be1[h])
    {
        float wl[8], bb[8];
        #pragma unroll
        for (int ct = 0; ct < 8; ++ct) {
            wl[ct] = wlast[ct * 16 + lrow];
            bb[ct] = be1f[ct * 16 + lrow];
        }
        if (nseg == 1) {
            const float* qb = Q + (int)sseg_b[0] * (NCH * HD);
            float qv[3][8];
            #pragma unroll
            for (int c = 0; c < 3; ++c)
                #pragma unroll
                for (int ct = 0; ct < 8; ++ct)
                    qv[c][ct] = qb[c * 128 + ct * 16 + lrow];
            #pragma unroll
            for (int r = 0; r < 4; ++r) {
                int nl = wave * 16 + rq + r;
                #pragma unroll
                for (int c = 0; c < 3; ++c) {
                    int row = c * 64 + nl;
                    float rad = *(const float*)&e_buf[row * ESTR + 134];
                    #pragma unroll
                    for (int ct = 0; ct < 8; ++ct) {
                        float x = acc1[ct][r] + bb[ct] + qv[c][ct] + rad * wl[ct];
                        e_buf[row * ESTR + ct * 16 + lrow] = f2bf(silu_f(x));
                    }
                }
            }
        } else {
            #pragma unroll
            for (int r = 0; r < 4; ++r) {
                int nl = wave * 16 + rq + r;
                int b  = sbatch[nl];
                #pragma unroll
                for (int c = 0; c < 3; ++c) {
                    int row = c * 64 + nl;
                    float rad = *(const float*)&e_buf[row * ESTR + 134];
                    const float* qb = Q + (b * 3 + c) * 128;
                    #pragma unroll
                    for (int ct = 0; ct < 8; ++ct) {
                        float x = acc1[ct][r] + bb[ct] + qb[ct * 16 + lrow] + rad * wl[ct];
                        e_buf[row * ESTR + ct * 16 + lrow] = f2bf(silu_f(x));
                    }
                }
            }
        }
    }
    // (no barrier: wave w's chunks {w, w+4, w+8} are exactly the rows it wrote)

    // ---- GEMM2: M = silu(E1 @ We2 + be2); wave w -> chunks w+4j (channel j) ----
    f32x4 acc2[3][8] = {};
    for (int ks = 0; ks < 4; ++ks) {
        short8 af[3];
        for (int j = 0; j < 3; ++j)
            af[j] = *(const short8*)(&e_buf[(j * 64 + wave * 16 + lrow) * ESTR +
                                            ks * 32 + lkb]);
        for (int ct = 0; ct < 8; ++ct) {
            short8 bfg = *(const short8*)(w2r + ((ct * 4 + ks) * 64 + lane) * 8);
            for (int j = 0; j < 3; ++j)
                acc2[j][ct] = MFMA_16x16x32(af[j], bfg, acc2[j][ct]);
        }
    }
    // Epilogue 2: write M (bf16) + fast-path per-channel segment-sum to global
    {
        const int bagg = (nseg == 1) ? (int)sseg_b[0] * (NCH * HD) : 0;
        for (int j = 0; j < 3; ++j) {
            for (int ct = 0; ct < 8; ++ct) {
                int h = ct * 16 + lrow;
                float bb = be2f[h];
                float psum = 0.0f;
                #pragma unroll
                for (int r = 0; r < 4; ++r) {
                    int row = j * 64 + wave * 16 + rq + r;
                    float v = silu_f(acc2[j][ct][r] + bb);
                    e_buf[row * ESTR + h] = f2bf(v);
                    psum += v;
                }
                if (nseg == 1) {
                    psum += __shfl_xor(psum, 16, 64);
                    psum += __shfl_xor(psum, 32, 64);
                    if (lane < 16)
                        atomicAdd(&aggsum[bagg + j * 128 + ct * 16 + lane], psum);
                }
            }
        }
    }

    // ---- GEMM3: SH = silu(M @ Wc1 + bc1); s = SH . Wc2 (never materialized) ----
    f32x4 acc3[3][8] = {};
    for (int ks = 0; ks < 4; ++ks) {
        short8 af[3];
        for (int j = 0; j < 3; ++j)
            af[j] = *(const short8*)(&e_buf[(j * 64 + wave * 16 + lrow) * ESTR +
                                            ks * 32 + lkb]);
        for (int ct = 0; ct < 8; ++ct) {
            short8 bfg = *(const short8*)(wc1r + ((ct * 4 + ks) * 64 + lane) * 8);
            for (int j = 0; j < 3; ++j)
                acc3[j][ct] = MFMA_16x16x32(af[j], bfg, acc3[j][ct]);
        }
    }
    for (int j = 0; j < 3; ++j) {
        float p0 = 0.f, p1 = 0.f, p2 = 0.f, p3 = 0.f;
        for (int ct = 0; ct < 8; ++ct) {
            int h = ct * 16 + lrow;
            float bb = bc1f[h];
            float w2 = wc2f[h];
            p0 += silu_f(acc3[j][ct][0] + bb) * w2;
            p1 += silu_f(acc3[j][ct][1] + bb) * w2;
            p2 += silu_f(acc3[j][ct][2] + bb) * w2;
            p3 += silu_f(acc3[j][ct][3] + bb) * w2;
        }
        #pragma unroll
        for (int off = 1; off < 16; off <<= 1) {
            p0 += __shfl_xor(p0, off, 64);
            p1 += __shfl_xor(p1, off, 64);
            p2 += __shfl_xor(p2, off, 64);
            p3 += __shfl_xor(p3, off, 64);
        }
        if (lrow == 0) {
            int rbase = j * 64 + wave * 16 + rq;
            s_s[rbase + 0] = p0;
            s_s[rbase + 1] = p1;
            s_s[rbase + 2] = p2;
            s_s[rbase + 3] = p3;
        }
    }
    __syncthreads();

    // ---- Reduce to global (aggsum fast path already done in epilogue 2) ----
    if (nseg == 1) {
        int b = sseg_b[0];
        if (wave == 0) {   // trans: 64-lane shuffle tree over nodes
            float t[9];
            #pragma unroll
            for (int c = 0; c < 3; ++c) {
                int row = c * 64 + lane;
                float sv = s_s[row];
                float dx = *(const float*)&e_buf[row * ESTR + 128];
                float dy = *(const float*)&e_buf[row * ESTR + 130];
                float dz = *(const float*)&e_buf[row * ESTR + 132];
                t[0 * 3 + c] = dx * sv;
                t[1 * 3 + c] = dy * sv;
                t[2 * 3 + c] = dz * sv;
            }
            #pragma unroll
            for (int off = 1; off < 64; off <<= 1)
                #pragma unroll
                for (int k = 0; k < 9; ++k)
                    t[k] += __shfl_xor(t[k], off, 64);
            if (lane < 9)
                atomicAdd(&transsum[b * 9 + lane],
                          __shfl(t[lane], 0, 64));  // lane0 holds full sums
            if (lane == 0) atomicAdd(&cnt[b], 64.0f);
        }
    } else {
        for (int sg = 0; sg < nseg; ++sg) {
            int s0 = sseg_start[sg], s1 = sseg_start[sg + 1], b = sseg_b[sg];
            for (int idx = tid; idx < NCH * HD; idx += 256) {
                int c = idx >> 7, h = idx & 127;
                float sum = 0.f;
                for (int ii = s0; ii < s1; ++ii)
                    sum += bf2f(e_buf[(c * 64 + ii) * ESTR + h]);
                atomicAdd(&aggsum[(b * 3 + c) * 128 + h], sum);
            }
            if (tid < 9) {
                int d = tid / 3, c = tid % 3;
                float sum = 0.f;
                for (int ii = s0; ii < s1; ++ii)
                    sum += (*(const float*)&e_buf[(c * 64 + ii) * ESTR + 128 + 2 * d])
                           * s_s[c * 64 + ii];
                atomicAdd(&transsum[b * 9 + d * 3 + c], sum);
            }
            if (tid == 0) atomicAdd(&cnt[b], (float)(s1 - s0));
        }
    }
}

// ---------------------------------------------------------------------------
// Finalize: one block per (b,c) row. Means, node model, residuals, outputs.
// ---------------------------------------------------------------------------
__global__ void finalize_kernel(const float* __restrict__ vnf,
                                const float* __restrict__ vcoord,
                                const float* __restrict__ Wn1,
                                const float* __restrict__ bn1,
                                const float* __restrict__ Wn2,
                                const float* __restrict__ bn2,
                                const float* __restrict__ aggsum,
                                const float* __restrict__ transsum,
                                const float* __restrict__ cnt,
                                float* __restrict__ out) {
    int b = blockIdx.x / NCH;
    int c = blockIdx.x % NCH;
    int j = threadIdx.x;   // 0..127
    __shared__ float nin[256];
    __shared__ float h1[128];
    float count = fmaxf(cnt[b], 1.0f);
    nin[j]       = vnf[(b * 128 + j) * 3 + c];
    nin[128 + j] = aggsum[(b * 3 + c) * 128 + j] / count;
    __syncthreads();
    float x = bn1[j];
    for (int k = 0; k < 256; ++k)
        x += nin[k] * Wn1[k * 128 + j];
    h1[j] = silu_f(x);
    __syncthreads();
    float y = bn2[j];
    for (int k = 0; k < 128; ++k)
        y += h1[k] * Wn2[k * 128 + j];
    out[(b * 128 + j) * 3 + c] = vnf[(b * 128 + j) * 3 + c] + y;
    if (c == 0 && j < 9) {
        out[NGRAPH * 128 * 3 + b * 9 + j] =
            vcoord[b * 9 + j] + transsum[b * 9 + j] / count;
    }
}

// ---------------------------------------------------------------------------
extern "C" void kernel_launch(void* const* d_in, const int* in_sizes, int n_in,
                              void* d_out, int out_size, void* d_ws, size_t ws_size,
                              hipStream_t stream) {
    const float* node_feat = (const float*)d_in[0];
    const float* coord     = (const float*)d_in[1];
    const float* vnf       = (const float*)d_in[2];
    const float* vcoord    = (const float*)d_in[3];
    const int*   batch     = (const int*)d_in[4];
    const float* We1 = (const float*)d_in[5];
    const float* be1 = (const float*)d_in[6];
    const float* We2 = (const float*)d_in[7];
    const float* be2 = (const float*)d_in[8];
    const float* Wc1 = (const float*)d_in[9];
    const float* bc1 = (const float*)d_in[10];
    const float* Wc2 = (const float*)d_in[11];
    const float* Wn1 = (const float*)d_in[12];
    const float* bn1 = (const float*)d_in[13];
    const float* Wn2 = (const float*)d_in[14];
    const float* bn2 = (const float*)d_in[15];

    char* ws = (char*)d_ws;
    float*          aggsum   = (float*)(ws + 0);          // 153600
    float*          transsum = (float*)(ws + 153600);     // 3600
    float*          cntp     = (float*)(ws + 157200);     // 400
    float*          Q        = (float*)(ws + 157600);     // 153600
    unsigned short* w1r      = (unsigned short*)(ws + 311200); // 32768
    unsigned short* w2r      = (unsigned short*)(ws + 343968); // 32768
    unsigned short* wc1r     = (unsigned short*)(ws + 376736); // 32768
    float*          wlast    = (float*)(ws + 409504);
    float*          be1f     = (float*)(ws + 410016);
    float*          be2f     = (float*)(ws + 410528);
    float*          bc1f     = (float*)(ws + 411040);
    float*          wc2f     = (float*)(ws + 411552);

    (void)hipMemsetAsync(d_ws, 0, 157600, stream);  // zero accumulators each call

    prep_kernel<<<192 + NGRAPH * NCH, 256, 0, stream>>>(
        We1, We2, Wc1, be1, be2, bc1, Wc2, vnf,
        w1r, w2r, wc1r, Q, wlast, be1f, be2f, bc1f, wc2f);

    egcl_main<<<NNODES / BN, 256, 0, stream>>>(
        node_feat, coord, vcoord, batch, w1r, w2r, wc1r, Q,
        wlast, be1f, be2f, bc1f, wc2f, aggsum, transsum, cntp);

    finalize_kernel<<<NGRAPH * NCH, 128, 0, stream>>>(
        vnf, vcoord, Wn1, bn1, Wn2, bn2, aggsum, transsum, cntp,
        (float*)d_out);
}